// Round 2
// baseline (257.299 us; speedup 1.0000x reference)
//
#include <hip/hip_runtime.h>

// YOLO v1 loss. pred/target: (16384, 7, 7, 30) fp32.
// R4: request-throughput attack. R2 (staged) and R3 (strided regs) both sat at
//   ~73us because both issue ~1 line-request per lane per load (stride-120B /
//   per-lane global_load_lds): ~94k requests/CU at ~1.9cy/req dominates.
//   Here: truly coalesced float4 global loads (lane i -> base+16i, 16 lines
//   per wave-instr = 4x fewer requests), redistribution via LDS ds_write_b128
//   (linear, conflict-free), ONE barrier, then per-cell float2 LDS reads.
//   Two 30KB buffers -> all 60 global loads in flight before any wait.

#define CH 30
#define CPB 256                   // cells per block
#define T 256                     // threads per block
#define TILE_F (CPB * CH)         // 7680 floats = 30720 B per tensor
#define TILE_V4 (TILE_F / 4)      // 1920 float4 per tensor

__global__ __launch_bounds__(T, 2)
void yolo_partial(const float* __restrict__ pred,
                  const float* __restrict__ targ,
                  float* __restrict__ partial) {
    __shared__ float tT[TILE_F];          // target tile
    __shared__ float tP[TILE_F];          // pred tile
    __shared__ float wave_sums[T / 64];

    const int tid = threadIdx.x;
    const long long fbase = (long long)blockIdx.x * TILE_F;

    // ---- coalesced stage: issue ALL global loads first (60 dwordx4 in
    //      flight per thread-pair of tensors), then LDS writes ----
    const float4* gt = (const float4*)(targ + fbase);
    const float4* gp = (const float4*)(pred + fbase);
    float4 rt[8], rp[8];
#pragma unroll
    for (int k = 0; k < 8; ++k) {
        const int v = tid + k * T;
        if (v < TILE_V4) rt[k] = gt[v];
    }
#pragma unroll
    for (int k = 0; k < 8; ++k) {
        const int v = tid + k * T;
        if (v < TILE_V4) rp[k] = gp[v];
    }
#pragma unroll
    for (int k = 0; k < 8; ++k) {
        const int v = tid + k * T;
        if (v < TILE_V4) *(float4*)(tT + 4 * v) = rt[k];
    }
#pragma unroll
    for (int k = 0; k < 8; ++k) {
        const int v = tid + k * T;
        if (v < TILE_V4) *(float4*)(tP + 4 * v) = rp[k];
    }
    __syncthreads();

    // ---- per-cell compute from LDS (float2 reads, 8B aligned) ----
    float sum;
    {
        const float2* t2 = (const float2*)(tT + tid * CH);
        const float2* p2 = (const float2*)(tP + tid * CH);
        float2 t[15], p[15];
#pragma unroll
        for (int k = 0; k < 15; ++k) t[k] = t2[k];
#pragma unroll
        for (int k = 0; k < 15; ++k) p[k] = p2[k];

        // channel map: t[0]=(c0,c1) t[1]=(c2,c3) t[2]=(c4,c5) t[3]=(c6,c7)
        //              t[4]=(c8,c9) t[5..14]=(c10..c29)
        const float t4 = t[2].x, t9 = t[4].y;
        const bool coo = t4 > 0.0f;

        // no-object loss (weight 0.5)
        const float d4 = p[2].x - t4;
        const float d9 = p[4].y - t9;
        sum = coo ? 0.0f : 0.5f * (d4 * d4 + d9 * d9);

        if (coo) {
            // class loss (channels 10..29)
            float cl = 0.0f;
#pragma unroll
            for (int k = 0; k < 10; ++k) {
                const float dx = p[5 + k].x - t[5 + k].x;
                const float dy = p[5 + k].y - t[5 + k].y;
                cl += dx * dx + dy * dy;
            }
            sum += cl;

            // target box 0 corners (reference's exact math incl. inverted inter)
            const float tltx = t[0].x - 0.5f * t[1].x;
            const float tlty = t[0].y - 0.5f * t[1].y;
            const float trbx = t[0].x + 0.5f * t[1].x;
            const float trby = t[0].y + 0.5f * t[1].y;
            const float area2 = (trbx - tltx) * (trby - tlty);

            // pred box 0: ch 0..4, pred box 1: ch 5..9
            const float b0x = p[0].x, b0y = p[0].y, b0w = p[1].x, b0h = p[1].y;
            const float b1x = p[2].y, b1y = p[3].x, b1w = p[3].y, b1h = p[4].x;

            float iou0, iou1;
            {
                const float pltx = b0x - 0.5f * b0w, plty = b0y - 0.5f * b0h;
                const float prbx = b0x + 0.5f * b0w, prby = b0y + 0.5f * b0h;
                const float ltx = fmaxf(pltx, tltx), lty = fmaxf(plty, tlty);
                const float rbx = fminf(prbx, trbx), rby = fminf(prby, trby);
                const float inter = ((rbx - ltx < 0.0f) ? 1.0f : 0.0f) *
                                    ((rby - lty < 0.0f) ? 1.0f : 0.0f);
                const float area1 = (prbx - pltx) * (prby - plty);
                iou0 = inter / (area1 + area2 - inter);
            }
            {
                const float pltx = b1x - 0.5f * b1w, plty = b1y - 0.5f * b1h;
                const float prbx = b1x + 0.5f * b1w, prby = b1y + 0.5f * b1h;
                const float ltx = fmaxf(pltx, tltx), lty = fmaxf(plty, tlty);
                const float rbx = fminf(prbx, trbx), rby = fminf(prby, trby);
                const float inter = ((rbx - ltx < 0.0f) ? 1.0f : 0.0f) *
                                    ((rby - lty < 0.0f) ? 1.0f : 0.0f);
                const float area1 = (prbx - pltx) * (prby - plty);
                iou1 = inter / (area1 + area2 - inter);
            }
            // jnp.argmax first-index tie-break: idx=1 only if strictly greater
            const bool idx1 = iou1 > iou0;

            // responsible pred box (static selects, no dynamic reg indexing)
            const float rpx = idx1 ? b1x : b0x;
            const float rpy = idx1 ? b1y : b0y;
            const float rpw = idx1 ? b1w : b0w;
            const float rph = idx1 ? b1h : b0h;
            const float rpc = idx1 ? p[4].y : p[2].x;
            // responsible target box
            const float rtx = idx1 ? t[2].y : t[0].x;
            const float rty = idx1 ? t[3].x : t[0].y;
            const float rtw = idx1 ? t[3].y : t[1].x;
            const float rth = idx1 ? t[4].x : t[1].y;
            const float rtc = idx1 ? t[4].y : t[2].x;

            // contain loss (weight 1)
            const float dc = rpc - rtc;
            sum += dc * dc;

            // localization loss (weight 5)
            const float dx = rpx - rtx;
            const float dy = rpy - rty;
            const float dw = sqrtf(rpw) - sqrtf(rtw);
            const float dh = sqrtf(rph) - sqrtf(rth);
            sum += 5.0f * (dx * dx + dy * dy + dw * dw + dh * dh);
        }
    }

    // block reduction: wave shuffle then LDS
#pragma unroll
    for (int off = 32; off > 0; off >>= 1)
        sum += __shfl_down(sum, off, 64);
    const int wave = tid >> 6;
    const int lane = tid & 63;
    if (lane == 0) wave_sums[wave] = sum;
    __syncthreads();
    if (tid == 0) {
        float tot = 0.0f;
#pragma unroll
        for (int w = 0; w < T / 64; ++w) tot += wave_sums[w];
        partial[blockIdx.x] = tot;
    }
}

__global__ __launch_bounds__(256)
void yolo_reduce(const float* __restrict__ partial, int n, float* __restrict__ out) {
    __shared__ float wave_sums[4];
    float s = 0.0f;
    const int n4 = n >> 2;
    const float4* p4 = (const float4*)partial;
    for (int v = threadIdx.x; v < n4; v += 256) {
        const float4 x = p4[v];
        s += (x.x + x.y) + (x.z + x.w);
    }
    // tail (n not multiple of 4)
    for (int v = (n4 << 2) + threadIdx.x; v < n; v += 256)
        s += partial[v];
#pragma unroll
    for (int off = 32; off > 0; off >>= 1)
        s += __shfl_down(s, off, 64);
    const int wave = threadIdx.x >> 6;
    const int lane = threadIdx.x & 63;
    if (lane == 0) wave_sums[wave] = s;
    __syncthreads();
    if (threadIdx.x == 0) {
        const float tot = wave_sums[0] + wave_sums[1] + wave_sums[2] + wave_sums[3];
        out[0] = tot * (1.0f / 16384.0f);
    }
}

extern "C" void kernel_launch(void* const* d_in, const int* in_sizes, int n_in,
                              void* d_out, int out_size, void* d_ws, size_t ws_size,
                              hipStream_t stream) {
    const float* pred = (const float*)d_in[0];
    const float* targ = (const float*)d_in[1];
    float* out = (float*)d_out;
    float* partial = (float*)d_ws;

    const int n_cells = in_sizes[0] / CH;              // 802816 (divisible by 256)
    const int blocks = n_cells / CPB;                  // 3136

    yolo_partial<<<blocks, T, 0, stream>>>(pred, targ, partial);
    yolo_reduce<<<1, 256, 0, stream>>>(partial, blocks, out);
}

// Round 3
// 204.436 us; speedup vs baseline: 1.2586x; 1.2586x over previous
//
#include <hip/hip_runtime.h>

// YOLO v1 loss. pred/target: (16384, 7, 7, 30) fp32.
// R5: single-phase gload_lds, fine-grained blocks.
//   R4 post-mortem: reg-staging spilled to scratch (WRITE_SIZE 188MB) but
//   proved the memory system does >3 TB/s. R2 post-mortem: gload_lds is
//   spill-free; its limiter was 3 dependent barrier-drains per block.
//   Here: 64-thread / 64-cell blocks (15.4KB LDS -> 10 blocks/CU). Both
//   tensor tiles staged direct-to-LDS with ALL loads issued before the ONE
//   vmcnt-drain barrier; compute reads LDS; single-wave shuffle reduction
//   (no second barrier). 10 staggered blocks/CU keep HBM continuously fed.

#define CH 30
#define CPB 64                    // cells per block
#define T 64                      // threads per block (one wave)
#define TILE_F (CPB * CH)         // 1920 floats = 7680 B per tensor
#define TILE_V4 (TILE_F / 4)      // 480 float4 per tensor

typedef __attribute__((address_space(3))) void* lds_vp;
typedef const __attribute__((address_space(1))) void* gvp;

__global__ __launch_bounds__(T, 2)
void yolo_partial(const float* __restrict__ pred,
                  const float* __restrict__ targ,
                  float* __restrict__ partial) {
    __shared__ float tile[2 * TILE_F];   // [0..1919]=target, [1920..3839]=pred

    const int tid = threadIdx.x;
    const long long fbase = (long long)blockIdx.x * TILE_F;

    // ---- stage BOTH tiles direct-to-LDS, all loads in flight, no regs ----
    const float4* gt = (const float4*)(targ + fbase);
    const float4* gp = (const float4*)(pred + fbase);
#pragma unroll
    for (int k = 0; k < 8; ++k) {
        const int v = tid + k * T;
        if (v < TILE_V4)
            __builtin_amdgcn_global_load_lds((gvp)(gt + v), (lds_vp)(tile + 4 * v),
                                             16, 0, 0);
    }
#pragma unroll
    for (int k = 0; k < 8; ++k) {
        const int v = tid + k * T;
        if (v < TILE_V4)
            __builtin_amdgcn_global_load_lds((gvp)(gp + v),
                                             (lds_vp)(tile + TILE_F + 4 * v),
                                             16, 0, 0);
    }
    __syncthreads();   // one drain: vmcnt(0) + barrier

    // ---- per-cell compute from LDS (float2 reads, 8B aligned) ----
    float sum;
    {
        const float2* t2 = (const float2*)(tile + tid * CH);
        const float2* p2 = (const float2*)(tile + TILE_F + tid * CH);
        float2 t[15], p[15];
#pragma unroll
        for (int k = 0; k < 15; ++k) t[k] = t2[k];
#pragma unroll
        for (int k = 0; k < 15; ++k) p[k] = p2[k];

        // channel map: t[0]=(c0,c1) t[1]=(c2,c3) t[2]=(c4,c5) t[3]=(c6,c7)
        //              t[4]=(c8,c9) t[5..14]=(c10..c29)
        const float t4 = t[2].x, t9 = t[4].y;
        const bool coo = t4 > 0.0f;

        // no-object loss (weight 0.5)
        const float d4 = p[2].x - t4;
        const float d9 = p[4].y - t9;
        sum = coo ? 0.0f : 0.5f * (d4 * d4 + d9 * d9);

        if (coo) {
            // class loss (channels 10..29)
            float cl = 0.0f;
#pragma unroll
            for (int k = 0; k < 10; ++k) {
                const float dx = p[5 + k].x - t[5 + k].x;
                const float dy = p[5 + k].y - t[5 + k].y;
                cl += dx * dx + dy * dy;
            }
            sum += cl;

            // target box 0 corners (reference's exact math incl. inverted inter)
            const float tltx = t[0].x - 0.5f * t[1].x;
            const float tlty = t[0].y - 0.5f * t[1].y;
            const float trbx = t[0].x + 0.5f * t[1].x;
            const float trby = t[0].y + 0.5f * t[1].y;
            const float area2 = (trbx - tltx) * (trby - tlty);

            // pred box 0: ch 0..4, pred box 1: ch 5..9
            const float b0x = p[0].x, b0y = p[0].y, b0w = p[1].x, b0h = p[1].y;
            const float b1x = p[2].y, b1y = p[3].x, b1w = p[3].y, b1h = p[4].x;

            float iou0, iou1;
            {
                const float pltx = b0x - 0.5f * b0w, plty = b0y - 0.5f * b0h;
                const float prbx = b0x + 0.5f * b0w, prby = b0y + 0.5f * b0h;
                const float ltx = fmaxf(pltx, tltx), lty = fmaxf(plty, tlty);
                const float rbx = fminf(prbx, trbx), rby = fminf(prby, trby);
                const float inter = ((rbx - ltx < 0.0f) ? 1.0f : 0.0f) *
                                    ((rby - lty < 0.0f) ? 1.0f : 0.0f);
                const float area1 = (prbx - pltx) * (prby - plty);
                iou0 = inter / (area1 + area2 - inter);
            }
            {
                const float pltx = b1x - 0.5f * b1w, plty = b1y - 0.5f * b1h;
                const float prbx = b1x + 0.5f * b1w, prby = b1y + 0.5f * b1h;
                const float ltx = fmaxf(pltx, tltx), lty = fmaxf(plty, tlty);
                const float rbx = fminf(prbx, trbx), rby = fminf(prby, trby);
                const float inter = ((rbx - ltx < 0.0f) ? 1.0f : 0.0f) *
                                    ((rby - lty < 0.0f) ? 1.0f : 0.0f);
                const float area1 = (prbx - pltx) * (prby - plty);
                iou1 = inter / (area1 + area2 - inter);
            }
            // jnp.argmax first-index tie-break: idx=1 only if strictly greater
            const bool idx1 = iou1 > iou0;

            // responsible pred box (static selects, no dynamic reg indexing)
            const float rpx = idx1 ? b1x : b0x;
            const float rpy = idx1 ? b1y : b0y;
            const float rpw = idx1 ? b1w : b0w;
            const float rph = idx1 ? b1h : b0h;
            const float rpc = idx1 ? p[4].y : p[2].x;
            // responsible target box
            const float rtx = idx1 ? t[2].y : t[0].x;
            const float rty = idx1 ? t[3].x : t[0].y;
            const float rtw = idx1 ? t[3].y : t[1].x;
            const float rth = idx1 ? t[4].x : t[1].y;
            const float rtc = idx1 ? t[4].y : t[2].x;

            // contain loss (weight 1)
            const float dc = rpc - rtc;
            sum += dc * dc;

            // localization loss (weight 5)
            const float dx = rpx - rtx;
            const float dy = rpy - rty;
            const float dw = sqrtf(rpw) - sqrtf(rtw);
            const float dh = sqrtf(rph) - sqrtf(rth);
            sum += 5.0f * (dx * dx + dy * dy + dw * dw + dh * dh);
        }
    }

    // single-wave reduction: shuffle only, no barrier
#pragma unroll
    for (int off = 32; off > 0; off >>= 1)
        sum += __shfl_down(sum, off, 64);
    if (tid == 0) partial[blockIdx.x] = sum;
}

__global__ __launch_bounds__(256)
void yolo_reduce(const float* __restrict__ partial, int n, float* __restrict__ out) {
    __shared__ float wave_sums[4];
    float s = 0.0f;
    const int n4 = n >> 2;
    const float4* p4 = (const float4*)partial;
    for (int v = threadIdx.x; v < n4; v += 256) {
        const float4 x = p4[v];
        s += (x.x + x.y) + (x.z + x.w);
    }
    // tail (n not multiple of 4)
    for (int v = (n4 << 2) + threadIdx.x; v < n; v += 256)
        s += partial[v];
#pragma unroll
    for (int off = 32; off > 0; off >>= 1)
        s += __shfl_down(s, off, 64);
    const int wave = threadIdx.x >> 6;
    const int lane = threadIdx.x & 63;
    if (lane == 0) wave_sums[wave] = s;
    __syncthreads();
    if (threadIdx.x == 0) {
        const float tot = wave_sums[0] + wave_sums[1] + wave_sums[2] + wave_sums[3];
        out[0] = tot * (1.0f / 16384.0f);
    }
}

extern "C" void kernel_launch(void* const* d_in, const int* in_sizes, int n_in,
                              void* d_out, int out_size, void* d_ws, size_t ws_size,
                              hipStream_t stream) {
    const float* pred = (const float*)d_in[0];
    const float* targ = (const float*)d_in[1];
    float* out = (float*)d_out;
    float* partial = (float*)d_ws;

    const int n_cells = in_sizes[0] / CH;              // 802816
    const int blocks = n_cells / CPB;                  // 12544

    yolo_partial<<<blocks, T, 0, stream>>>(pred, targ, partial);
    yolo_reduce<<<1, 256, 0, stream>>>(partial, blocks, out);
}